// Round 6
// baseline (36.668 us; speedup 1.0000x reference)
//
#include <hip/hip_runtime.h>
#include <math.h>

#define N_PTS   4000000
#define NQUADS  (N_PTS / 4)        // 1,000,000 quads; 1 quad = 4 pts = 3 float4
#define NTHREADS 256
#define NBLOCKS  ((NQUADS + NTHREADS - 1) / NTHREADS)   // 3907

typedef float vfloat4 __attribute__((ext_vector_type(4)));  // native vec for nt-store

// ---------------------------------------------------------------------------
// Main kernel: pose fused (thread 0 -> LDS -> barrier), 1 quad per thread,
// per-block deterministic reduction -> partials[block].
// Round-6: NONTEMPORAL stores via native ext_vector type (round-5 compile fix).
// Streaming output is never re-read -> nt bit keeps it from evicting the
// L3-resident input.
// ---------------------------------------------------------------------------
__global__ __launch_bounds__(NTHREADS) void proj_kernel(
    const float4* __restrict__ pts,
    const float* __restrict__ xp, const float* __restrict__ yp,
    const float* __restrict__ zp, const float* __restrict__ rollp,
    const float* __restrict__ pitchp, const float* __restrict__ yawp,
    float* __restrict__ vout, float* __restrict__ partials)
{
    __shared__ float sRT[12];
    __shared__ float sred[NTHREADS / 64];

    if (threadIdx.x == 0) {
        const float r = rollp[0], p = pitchp[0], ya = yawp[0];
        const float cr = cosf(r),  sr = sinf(r);
        const float cp = cosf(p),  sp = sinf(p);
        const float cy = cosf(ya), sy = sinf(ya);
        // R = Rx @ Ry @ Rz, row-major
        sRT[0] = cp * cy;                 sRT[1] = -cp * sy;                sRT[2] = sp;
        sRT[3] = cr * sy + sr * sp * cy;  sRT[4] = cr * cy - sr * sp * sy;  sRT[5] = -sr * cp;
        sRT[6] = sr * sy - cr * sp * cy;  sRT[7] = sr * cy + cr * sp * sy;  sRT[8] = cr * cp;
        sRT[9] = xp[0]; sRT[10] = yp[0]; sRT[11] = zp[0];
    }
    __syncthreads();

    const float R00 = sRT[0], R01 = sRT[1], R02 = sRT[2];
    const float R10 = sRT[3], R11 = sRT[4], R12 = sRT[5];
    const float R20 = sRT[6], R21 = sRT[7], R22 = sRT[8];
    const float Tx  = sRT[9], Ty  = sRT[10], Tz = sRT[11];

    const int q = blockIdx.x * NTHREADS + threadIdx.x;
    float acc = 0.0f;

    if (q < NQUADS) {
        const float4 a = pts[3 * q + 0];
        const float4 b = pts[3 * q + 1];
        const float4 c = pts[3 * q + 2];

        const float px[4] = {a.x, a.w, b.z, c.y};
        const float py[4] = {a.y, b.x, b.w, c.z};
        const float pz[4] = {a.z, b.y, c.x, c.w};
        float vx[4], vy[4], vz[4];

#pragma unroll
        for (int k = 0; k < 4; ++k) {
            const float q0 = px[k] - Tx;
            const float q1 = py[k] - Ty;
            const float q2 = pz[k] - Tz;
            // v = q @ R   (v_j = sum_i q_i * R[i][j])
            const float v0 = q0 * R00 + q1 * R10 + q2 * R20;
            const float v1 = q0 * R01 + q1 * R11 + q2 * R21;
            const float v2 = q0 * R02 + q1 * R12 + q2 * R22;

            const bool dist = (v2 > 1.0f) && (v2 < 10.0f);

            // ph = v @ K^T ; ph[2] == v2
            const float ph0 = v0 * 600.0f + v2 * 640.0f;
            const float ph1 = v1 * 600.0f + v2 * 360.0f;
            const float u = ph0 / v2;            // IEEE div: mask-exactness
            const float w = ph1 / v2;
            const bool fov = (v2 > 0.0f) && (u > 1.0f) && (u < 1279.0f) &&
                             (w > 1.0f) && (w < 719.0f);
            const bool m = dist && fov;

            const float d = sqrtf(v0 * v0 + v1 * v1 + v2 * v2);
            const float t = (d - 4.0f) * 0.5f;   // (d - MU) / SIGMA
            acc += m ? __expf(-0.5f * t * t) : 0.0f;

            vx[k] = m ? v0 : 0.0f;
            vy[k] = m ? v1 : 0.0f;
            vz[k] = m ? v2 : 0.0f;
        }

        vfloat4* __restrict__ dst = (vfloat4*)(vout + (size_t)12 * q);
        const vfloat4 o0 = {vx[0], vy[0], vz[0], vx[1]};
        const vfloat4 o1 = {vy[1], vz[1], vx[2], vy[2]};
        const vfloat4 o2 = {vz[2], vx[3], vy[3], vz[3]};
        __builtin_nontemporal_store(o0, dst + 0);
        __builtin_nontemporal_store(o1, dst + 1);
        __builtin_nontemporal_store(o2, dst + 2);
    }

    // Per-block deterministic reduction (acc=0 for out-of-range threads).
#pragma unroll
    for (int off = 32; off > 0; off >>= 1)
        acc += __shfl_down(acc, off, 64);
    if ((threadIdx.x & 63) == 0) sred[threadIdx.x >> 6] = acc;
    __syncthreads();
    if (threadIdx.x == 0) {
        float tot = 0.0f;
#pragma unroll
        for (int i = 0; i < NTHREADS / 64; ++i) tot += sred[i];
        partials[blockIdx.x] = tot;
    }
}

// ---------------------------------------------------------------------------
// Loss kernel: sum partials in fixed order -> loss. Separate dispatch =
// the cheap cross-block synchronization point (no device-scope fences).
// ---------------------------------------------------------------------------
__global__ __launch_bounds__(256) void loss_kernel(const float* __restrict__ partials,
                                                   int n, float* __restrict__ loss_out) {
    __shared__ float sdata[4];
    float acc = 0.0f;
    for (int i = threadIdx.x; i < n; i += 256) acc += partials[i];
#pragma unroll
    for (int off = 32; off > 0; off >>= 1)
        acc += __shfl_down(acc, off, 64);
    if ((threadIdx.x & 63) == 0) sdata[threadIdx.x >> 6] = acc;
    __syncthreads();
    if (threadIdx.x == 0) {
        const float tot = sdata[0] + sdata[1] + sdata[2] + sdata[3];
        loss_out[0] = 1.0f / (tot + 1e-6f);
    }
}

extern "C" void kernel_launch(void* const* d_in, const int* in_sizes, int n_in,
                              void* d_out, int out_size, void* d_ws, size_t ws_size,
                              hipStream_t stream) {
    const float4* pts  = (const float4*)d_in[0];
    const float* x     = (const float*)d_in[1];
    const float* y     = (const float*)d_in[2];
    const float* z     = (const float*)d_in[3];
    const float* roll  = (const float*)d_in[4];
    const float* pitch = (const float*)d_in[5];
    const float* yaw   = (const float*)d_in[6];

    float* out   = (float*)d_out;   // [0..12M) verts, [12M] loss
    float* parts = (float*)d_ws;    // NBLOCKS floats

    proj_kernel<<<NBLOCKS, NTHREADS, 0, stream>>>(pts, x, y, z, roll, pitch, yaw,
                                                  out, parts);
    loss_kernel<<<1, 256, 0, stream>>>(parts, NBLOCKS, out + (size_t)3 * N_PTS);
}

// Round 9
// 35.950 us; speedup vs baseline: 1.0200x; 1.0200x over previous
//
#include <hip/hip_runtime.h>
#include <math.h>

#define N_PTS   4000000
#define NQUADS  (N_PTS / 4)         // 1,000,000 quads; 1 quad = 4 pts = 3 float4
#define NPAIRS  (NQUADS / 2)        // 500,000 threads, 2 quads (6 float4) each
#define NTHREADS 256
#define NBLOCKS  ((NPAIRS + NTHREADS - 1) / NTHREADS)   // 1954

// readfirstlane is i32-typed: MUST bit-cast floats (round-8 lesson: implicit
// float->int VALUE conversion silently destroyed R).
__device__ __forceinline__ float rfl_f32(float x) {
    return __int_as_float(__builtin_amdgcn_readfirstlane(__float_as_int(x)));
}

// ---------------------------------------------------------------------------
// Round 9 = round 8 with readfirstlane bit-cast fix.
// Latency-hiding attack: 2 quads per thread, all 6 float4 loads issued up
// front (2x MLP vs round 4), live set kept under the 64-VGPR occupancy cliff:
// R,T pinned to SGPRs via rfl_f32, __launch_bounds__(256,8).
// Plain stores (round-6 lesson). No device fences (round-3 lesson).
// ---------------------------------------------------------------------------
__device__ __forceinline__ float do_quad(
    const float4 a, const float4 b, const float4 c,
    float R00, float R01, float R02,
    float R10, float R11, float R12,
    float R20, float R21, float R22,
    float Tx, float Ty, float Tz,
    float4* __restrict__ dst)
{
    const float px[4] = {a.x, a.w, b.z, c.y};
    const float py[4] = {a.y, b.x, b.w, c.z};
    const float pz[4] = {a.z, b.y, c.x, c.w};
    float vx[4], vy[4], vz[4];
    float acc = 0.0f;

#pragma unroll
    for (int k = 0; k < 4; ++k) {
        const float q0 = px[k] - Tx;
        const float q1 = py[k] - Ty;
        const float q2 = pz[k] - Tz;
        // v = q @ R   (v_j = sum_i q_i * R[i][j])
        const float v0 = q0 * R00 + q1 * R10 + q2 * R20;
        const float v1 = q0 * R01 + q1 * R11 + q2 * R21;
        const float v2 = q0 * R02 + q1 * R12 + q2 * R22;

        const bool dist = (v2 > 1.0f) && (v2 < 10.0f);

        // ph = v @ K^T ; ph[2] == v2
        const float ph0 = v0 * 600.0f + v2 * 640.0f;
        const float ph1 = v1 * 600.0f + v2 * 360.0f;
        const float u = ph0 / v2;            // IEEE div: mask bit-exactness
        const float w = ph1 / v2;
        const bool fov = (v2 > 0.0f) && (u > 1.0f) && (u < 1279.0f) &&
                         (w > 1.0f) && (w < 719.0f);
        const bool m = dist && fov;

        const float d = sqrtf(v0 * v0 + v1 * v1 + v2 * v2);
        const float t = (d - 4.0f) * 0.5f;   // (d - MU) / SIGMA
        acc += m ? __expf(-0.5f * t * t) : 0.0f;

        vx[k] = m ? v0 : 0.0f;
        vy[k] = m ? v1 : 0.0f;
        vz[k] = m ? v2 : 0.0f;
    }

    dst[0] = make_float4(vx[0], vy[0], vz[0], vx[1]);
    dst[1] = make_float4(vy[1], vz[1], vx[2], vy[2]);
    dst[2] = make_float4(vz[2], vx[3], vy[3], vz[3]);
    return acc;
}

__global__ __launch_bounds__(NTHREADS, 8) void proj_kernel(
    const float4* __restrict__ pts,
    const float* __restrict__ xp, const float* __restrict__ yp,
    const float* __restrict__ zp, const float* __restrict__ rollp,
    const float* __restrict__ pitchp, const float* __restrict__ yawp,
    float4* __restrict__ vout, float* __restrict__ partials)
{
    __shared__ float sRT[12];
    __shared__ float sred[NTHREADS / 64];

    if (threadIdx.x == 0) {
        const float r = rollp[0], p = pitchp[0], ya = yawp[0];
        const float cr = cosf(r),  sr = sinf(r);
        const float cp = cosf(p),  sp = sinf(p);
        const float cy = cosf(ya), sy = sinf(ya);
        // R = Rx @ Ry @ Rz, row-major
        sRT[0] = cp * cy;                 sRT[1] = -cp * sy;                sRT[2] = sp;
        sRT[3] = cr * sy + sr * sp * cy;  sRT[4] = cr * cy - sr * sp * sy;  sRT[5] = -sr * cp;
        sRT[6] = sr * sy - cr * sp * cy;  sRT[7] = sr * cy + cr * sp * sy;  sRT[8] = cr * cp;
        sRT[9] = xp[0]; sRT[10] = yp[0]; sRT[11] = zp[0];
    }
    __syncthreads();

    // Pin R,T to SGPRs (block-uniform values): frees 12 VGPRs.
    const float R00 = rfl_f32(sRT[0]);
    const float R01 = rfl_f32(sRT[1]);
    const float R02 = rfl_f32(sRT[2]);
    const float R10 = rfl_f32(sRT[3]);
    const float R11 = rfl_f32(sRT[4]);
    const float R12 = rfl_f32(sRT[5]);
    const float R20 = rfl_f32(sRT[6]);
    const float R21 = rfl_f32(sRT[7]);
    const float R22 = rfl_f32(sRT[8]);
    const float Tx  = rfl_f32(sRT[9]);
    const float Ty  = rfl_f32(sRT[10]);
    const float Tz  = rfl_f32(sRT[11]);

    const int pair = blockIdx.x * NTHREADS + threadIdx.x;
    float acc = 0.0f;

    if (pair < NPAIRS) {
        const float4* __restrict__ src = pts + (size_t)6 * pair;
        // Issue all 6 loads up front: 2x memory-level parallelism.
        const float4 a0 = src[0];
        const float4 a1 = src[1];
        const float4 a2 = src[2];
        const float4 b0 = src[3];
        const float4 b1 = src[4];
        const float4 b2 = src[5];

        float4* __restrict__ dst = vout + (size_t)6 * pair;
        acc  = do_quad(a0, a1, a2, R00, R01, R02, R10, R11, R12,
                       R20, R21, R22, Tx, Ty, Tz, dst);
        acc += do_quad(b0, b1, b2, R00, R01, R02, R10, R11, R12,
                       R20, R21, R22, Tx, Ty, Tz, dst + 3);
    }

    // Per-block deterministic reduction (acc=0 for out-of-range threads).
#pragma unroll
    for (int off = 32; off > 0; off >>= 1)
        acc += __shfl_down(acc, off, 64);
    if ((threadIdx.x & 63) == 0) sred[threadIdx.x >> 6] = acc;
    __syncthreads();
    if (threadIdx.x == 0) {
        float tot = 0.0f;
#pragma unroll
        for (int i = 0; i < NTHREADS / 64; ++i) tot += sred[i];
        partials[blockIdx.x] = tot;
    }
}

// ---------------------------------------------------------------------------
// Loss kernel: sum partials in fixed order -> loss (cross-block sync point).
// ---------------------------------------------------------------------------
__global__ __launch_bounds__(256) void loss_kernel(const float* __restrict__ partials,
                                                   int n, float* __restrict__ loss_out) {
    __shared__ float sdata[4];
    float acc = 0.0f;
    for (int i = threadIdx.x; i < n; i += 256) acc += partials[i];
#pragma unroll
    for (int off = 32; off > 0; off >>= 1)
        acc += __shfl_down(acc, off, 64);
    if ((threadIdx.x & 63) == 0) sdata[threadIdx.x >> 6] = acc;
    __syncthreads();
    if (threadIdx.x == 0) {
        const float tot = sdata[0] + sdata[1] + sdata[2] + sdata[3];
        loss_out[0] = 1.0f / (tot + 1e-6f);
    }
}

extern "C" void kernel_launch(void* const* d_in, const int* in_sizes, int n_in,
                              void* d_out, int out_size, void* d_ws, size_t ws_size,
                              hipStream_t stream) {
    const float4* pts  = (const float4*)d_in[0];
    const float* x     = (const float*)d_in[1];
    const float* y     = (const float*)d_in[2];
    const float* z     = (const float*)d_in[3];
    const float* roll  = (const float*)d_in[4];
    const float* pitch = (const float*)d_in[5];
    const float* yaw   = (const float*)d_in[6];

    float* out   = (float*)d_out;   // [0..12M) verts, [12M] loss
    float* parts = (float*)d_ws;    // NBLOCKS floats

    proj_kernel<<<NBLOCKS, NTHREADS, 0, stream>>>(pts, x, y, z, roll, pitch, yaw,
                                                  (float4*)out, parts);
    loss_kernel<<<1, 256, 0, stream>>>(parts, NBLOCKS, out + (size_t)3 * N_PTS);
}

// Round 10
// 28.911 us; speedup vs baseline: 1.2683x; 1.2435x over previous
//
#include <hip/hip_runtime.h>
#include <math.h>

#define N_PTS   4000000
#define NQUADS  (N_PTS / 4)        // 1,000,000 quads; 1 quad = 4 pts = 12 floats
#define NTHREADS 256
#define NBLOCKS  ((NQUADS + NTHREADS - 1) / NTHREADS)   // 3907
#define NF4      (3 * NQUADS)      // 3,000,000 float4s in the point stream

// ---------------------------------------------------------------------------
// Round 10: LDS tile transpose. Theory: the 48B/lane stride made every
// global load/store instruction span 48 cache lines (vs 16 for a pure
// stream). Stage a 12 KiB block tile through LDS so ALL global accesses are
// lane-contiguous float4 (copy-kernel pattern); threads read/write their own
// 48B LDS region (ds_*_b128, minimum-conflict banking).
// Structure otherwise = round 4 (best): 1 quad/thread, pose fused, plain
// stores, no device fences, separate loss dispatch.
// ---------------------------------------------------------------------------
__global__ __launch_bounds__(NTHREADS) void proj_kernel(
    const float4* __restrict__ pts,
    const float* __restrict__ xp, const float* __restrict__ yp,
    const float* __restrict__ zp, const float* __restrict__ rollp,
    const float* __restrict__ pitchp, const float* __restrict__ yawp,
    float4* __restrict__ vout, float* __restrict__ partials)
{
    __shared__ float sRT[12];
    __shared__ float4 tile[NTHREADS * 3];      // 12 KiB
    __shared__ float sred[NTHREADS / 64];

    const int t = threadIdx.x;
    const size_t f4base = (size_t)blockIdx.x * (NTHREADS * 3);
    const size_t i0 = f4base + t;
    const size_t i1 = i0 + NTHREADS;
    const size_t i2 = i1 + NTHREADS;

    if (t == 0) {
        const float r = rollp[0], p = pitchp[0], ya = yawp[0];
        const float cr = cosf(r),  sr = sinf(r);
        const float cp = cosf(p),  sp = sinf(p);
        const float cy = cosf(ya), sy = sinf(ya);
        // R = Rx @ Ry @ Rz, row-major
        sRT[0] = cp * cy;                 sRT[1] = -cp * sy;                sRT[2] = sp;
        sRT[3] = cr * sy + sr * sp * cy;  sRT[4] = cr * cy - sr * sp * sy;  sRT[5] = -sr * cp;
        sRT[6] = sr * sy - cr * sp * cy;  sRT[7] = sr * cy + cr * sp * sy;  sRT[8] = cr * cp;
        sRT[9] = xp[0]; sRT[10] = yp[0]; sRT[11] = zp[0];
    }

    // Coalesced tile load (lane stride 16B).
    if (i0 < NF4) tile[t]                = pts[i0];
    if (i1 < NF4) tile[t + NTHREADS]     = pts[i1];
    if (i2 < NF4) tile[t + 2 * NTHREADS] = pts[i2];
    __syncthreads();

    const float R00 = sRT[0], R01 = sRT[1], R02 = sRT[2];
    const float R10 = sRT[3], R11 = sRT[4], R12 = sRT[5];
    const float R20 = sRT[6], R21 = sRT[7], R22 = sRT[8];
    const float Tx  = sRT[9], Ty  = sRT[10], Tz = sRT[11];

    const int q = blockIdx.x * NTHREADS + t;
    float acc = 0.0f;

    if (q < NQUADS) {
        // Own 48B region: 3x ds_read_b128 (8 lanes cover all 32 banks).
        const float4* __restrict__ mt = (const float4*)((const float*)tile + 12 * t);
        const float4 a = mt[0];
        const float4 b = mt[1];
        const float4 c = mt[2];

        const float px[4] = {a.x, a.w, b.z, c.y};
        const float py[4] = {a.y, b.x, b.w, c.z};
        const float pz[4] = {a.z, b.y, c.x, c.w};
        float vx[4], vy[4], vz[4];

#pragma unroll
        for (int k = 0; k < 4; ++k) {
            const float q0 = px[k] - Tx;
            const float q1 = py[k] - Ty;
            const float q2 = pz[k] - Tz;
            // v = q @ R   (v_j = sum_i q_i * R[i][j])
            const float v0 = q0 * R00 + q1 * R10 + q2 * R20;
            const float v1 = q0 * R01 + q1 * R11 + q2 * R21;
            const float v2 = q0 * R02 + q1 * R12 + q2 * R22;

            const bool dist = (v2 > 1.0f) && (v2 < 10.0f);

            // ph = v @ K^T ; ph[2] == v2
            const float ph0 = v0 * 600.0f + v2 * 640.0f;
            const float ph1 = v1 * 600.0f + v2 * 360.0f;
            const float u = ph0 / v2;            // IEEE div: mask bit-exactness
            const float w = ph1 / v2;
            const bool fov = (v2 > 0.0f) && (u > 1.0f) && (u < 1279.0f) &&
                             (w > 1.0f) && (w < 719.0f);
            const bool m = dist && fov;

            const float d = sqrtf(v0 * v0 + v1 * v1 + v2 * v2);
            const float t2 = (d - 4.0f) * 0.5f;  // (d - MU) / SIGMA
            acc += m ? __expf(-0.5f * t2 * t2) : 0.0f;

            vx[k] = m ? v0 : 0.0f;
            vy[k] = m ? v1 : 0.0f;
            vz[k] = m ? v2 : 0.0f;
        }

        // Write results to own region (same banking as read; no cross-thread
        // hazard with the strided reads, so no extra barrier needed here).
        float4* __restrict__ mtw = (float4*)((float*)tile + 12 * t);
        mtw[0] = make_float4(vx[0], vy[0], vz[0], vx[1]);
        mtw[1] = make_float4(vy[1], vz[1], vx[2], vy[2]);
        mtw[2] = make_float4(vz[2], vx[3], vy[3], vz[3]);
    }
    __syncthreads();

    // Coalesced tile store (lane stride 16B).
    if (i0 < NF4) vout[i0] = tile[t];
    if (i1 < NF4) vout[i1] = tile[t + NTHREADS];
    if (i2 < NF4) vout[i2] = tile[t + 2 * NTHREADS];

    // Per-block deterministic reduction (acc=0 for out-of-range threads).
#pragma unroll
    for (int off = 32; off > 0; off >>= 1)
        acc += __shfl_down(acc, off, 64);
    if ((t & 63) == 0) sred[t >> 6] = acc;
    __syncthreads();
    if (t == 0) {
        float tot = 0.0f;
#pragma unroll
        for (int i = 0; i < NTHREADS / 64; ++i) tot += sred[i];
        partials[blockIdx.x] = tot;
    }
}

// ---------------------------------------------------------------------------
// Loss kernel: sum partials in fixed order -> loss (cross-block sync point).
// ---------------------------------------------------------------------------
__global__ __launch_bounds__(256) void loss_kernel(const float* __restrict__ partials,
                                                   int n, float* __restrict__ loss_out) {
    __shared__ float sdata[4];
    float acc = 0.0f;
    for (int i = threadIdx.x; i < n; i += 256) acc += partials[i];
#pragma unroll
    for (int off = 32; off > 0; off >>= 1)
        acc += __shfl_down(acc, off, 64);
    if ((threadIdx.x & 63) == 0) sdata[threadIdx.x >> 6] = acc;
    __syncthreads();
    if (threadIdx.x == 0) {
        const float tot = sdata[0] + sdata[1] + sdata[2] + sdata[3];
        loss_out[0] = 1.0f / (tot + 1e-6f);
    }
}

extern "C" void kernel_launch(void* const* d_in, const int* in_sizes, int n_in,
                              void* d_out, int out_size, void* d_ws, size_t ws_size,
                              hipStream_t stream) {
    const float4* pts  = (const float4*)d_in[0];
    const float* x     = (const float*)d_in[1];
    const float* y     = (const float*)d_in[2];
    const float* z     = (const float*)d_in[3];
    const float* roll  = (const float*)d_in[4];
    const float* pitch = (const float*)d_in[5];
    const float* yaw   = (const float*)d_in[6];

    float* out   = (float*)d_out;   // [0..12M) verts, [12M] loss
    float* parts = (float*)d_ws;    // NBLOCKS floats

    proj_kernel<<<NBLOCKS, NTHREADS, 0, stream>>>(pts, x, y, z, roll, pitch, yaw,
                                                  (float4*)out, parts);
    loss_kernel<<<1, 256, 0, stream>>>(parts, NBLOCKS, out + (size_t)3 * N_PTS);
}

// Round 11
// 26.307 us; speedup vs baseline: 1.3938x; 1.0990x over previous
//
#include <hip/hip_runtime.h>
#include <math.h>

#define N_PTS   4000000
#define NQUADS  (N_PTS / 4)        // 1,000,000 quads; 1 quad = 4 pts = 12 floats
#define NTHREADS 256
#define NF4      (3 * NQUADS)      // 3,000,000 float4s in the stream
#define NTILES   ((NQUADS + NTHREADS - 1) / NTHREADS)   // 3907 tiles of 256 quads
#define NBLOCKS_P ((NTILES + 1) / 2)                    // 1954 blocks, 2 tiles each

// ---------------------------------------------------------------------------
// Round 11: T14-style register prefetch. Round-10 LDS-transpose structure
// kept (coalesced global IO, own-48B LDS compute), but each block runs TWO
// tiles and issues tile i+1's 3 global loads into registers right after
// tile i's LDS reads — the ~700cy load latency hides under tile i's
// compute + store instead of sitting on the critical path. Thread-0 trig
// moved to overlap the prologue load latency. Single 12 KiB buffer keeps
// 8 blocks/CU. Plain stores; no device fences; separate loss dispatch.
// ---------------------------------------------------------------------------
__global__ __launch_bounds__(NTHREADS) void proj_kernel(
    const float4* __restrict__ pts,
    const float* __restrict__ xp, const float* __restrict__ yp,
    const float* __restrict__ zp, const float* __restrict__ rollp,
    const float* __restrict__ pitchp, const float* __restrict__ yawp,
    float4* __restrict__ vout, float* __restrict__ partials)
{
    __shared__ float sRT[12];
    __shared__ float4 tile[3 * NTHREADS];      // 12 KiB
    __shared__ float sred[NTHREADS / 64];

    const int t = threadIdx.x;
    const int tbase = blockIdx.x * 2;

    // --- prologue: issue tile0 loads, overlap thread-0 trig with latency ---
    float4 p0 = make_float4(0.f, 0.f, 0.f, 0.f), p1 = p0, p2 = p0;
    {
        const size_t fb = (size_t)tbase * (3 * NTHREADS) + t;
        if (fb                < NF4) p0 = pts[fb];
        if (fb +     NTHREADS < NF4) p1 = pts[fb + NTHREADS];
        if (fb + 2 * NTHREADS < NF4) p2 = pts[fb + 2 * NTHREADS];
    }
    if (t == 0) {
        const float r = rollp[0], p = pitchp[0], ya = yawp[0];
        const float cr = cosf(r),  sr = sinf(r);
        const float cp = cosf(p),  sp = sinf(p);
        const float cy = cosf(ya), sy = sinf(ya);
        // R = Rx @ Ry @ Rz, row-major
        sRT[0] = cp * cy;                 sRT[1] = -cp * sy;                sRT[2] = sp;
        sRT[3] = cr * sy + sr * sp * cy;  sRT[4] = cr * cy - sr * sp * sy;  sRT[5] = -sr * cp;
        sRT[6] = sr * sy - cr * sp * cy;  sRT[7] = sr * cy + cr * sp * sy;  sRT[8] = cr * cp;
        sRT[9] = xp[0]; sRT[10] = yp[0]; sRT[11] = zp[0];
    }
    tile[t]                = p0;
    tile[t + NTHREADS]     = p1;
    tile[t + 2 * NTHREADS] = p2;
    __syncthreads();                                    // tile0 + sRT visible

    const float R00 = sRT[0], R01 = sRT[1], R02 = sRT[2];
    const float R10 = sRT[3], R11 = sRT[4], R12 = sRT[5];
    const float R20 = sRT[6], R21 = sRT[7], R22 = sRT[8];
    const float Tx  = sRT[9], Ty  = sRT[10], Tz = sRT[11];

    float acc = 0.0f;

#pragma unroll
    for (int i = 0; i < 2; ++i) {
        const int tid = tbase + i;

        // Read own quad (3x ds_read_b128 from own 48B region).
        const float4* __restrict__ mt = (const float4*)((const float*)tile + 12 * t);
        const float4 a = mt[0];
        const float4 b = mt[1];
        const float4 c = mt[2];

        // Prefetch next tile -> regs; latency hides under compute + store.
        if (i == 0) {
            const size_t fb = (size_t)(tbase + 1) * (3 * NTHREADS) + t;
            p0 = make_float4(0.f, 0.f, 0.f, 0.f); p1 = p0; p2 = p0;
            if (fb                < NF4) p0 = pts[fb];
            if (fb +     NTHREADS < NF4) p1 = pts[fb + NTHREADS];
            if (fb + 2 * NTHREADS < NF4) p2 = pts[fb + 2 * NTHREADS];
        }

        const int q = tid * NTHREADS + t;               // global quad index
        float4 o0 = make_float4(0.f, 0.f, 0.f, 0.f), o1 = o0, o2 = o0;
        if (q < NQUADS) {
            const float px[4] = {a.x, a.w, b.z, c.y};
            const float py[4] = {a.y, b.x, b.w, c.z};
            const float pz[4] = {a.z, b.y, c.x, c.w};
            float vx[4], vy[4], vz[4];

#pragma unroll
            for (int k = 0; k < 4; ++k) {
                const float q0 = px[k] - Tx;
                const float q1 = py[k] - Ty;
                const float q2 = pz[k] - Tz;
                // v = q @ R   (v_j = sum_i q_i * R[i][j])
                const float v0 = q0 * R00 + q1 * R10 + q2 * R20;
                const float v1 = q0 * R01 + q1 * R11 + q2 * R21;
                const float v2 = q0 * R02 + q1 * R12 + q2 * R22;

                const bool dist = (v2 > 1.0f) && (v2 < 10.0f);

                // ph = v @ K^T ; ph[2] == v2
                const float ph0 = v0 * 600.0f + v2 * 640.0f;
                const float ph1 = v1 * 600.0f + v2 * 360.0f;
                const float u = ph0 / v2;        // IEEE div: mask bit-exactness
                const float w = ph1 / v2;
                const bool fov = (v2 > 0.0f) && (u > 1.0f) && (u < 1279.0f) &&
                                 (w > 1.0f) && (w < 719.0f);
                const bool m = dist && fov;

                const float d  = sqrtf(v0 * v0 + v1 * v1 + v2 * v2);
                const float t2 = (d - 4.0f) * 0.5f;     // (d - MU) / SIGMA
                acc += m ? __expf(-0.5f * t2 * t2) : 0.0f;

                vx[k] = m ? v0 : 0.0f;
                vy[k] = m ? v1 : 0.0f;
                vz[k] = m ? v2 : 0.0f;
            }
            o0 = make_float4(vx[0], vy[0], vz[0], vx[1]);
            o1 = make_float4(vy[1], vz[1], vx[2], vy[2]);
            o2 = make_float4(vz[2], vx[3], vy[3], vz[3]);
        }

        // Results to own region (only this thread touches it).
        float4* __restrict__ mtw = (float4*)((float*)tile + 12 * t);
        mtw[0] = o0; mtw[1] = o1; mtw[2] = o2;
        __syncthreads();                                // results visible

        // Coalesced store (lane stride 16B).
        {
            const size_t fb = (size_t)tid * (3 * NTHREADS) + t;
            if (fb                < NF4) vout[fb]                = tile[t];
            if (fb +     NTHREADS < NF4) vout[fb + NTHREADS]     = tile[t + NTHREADS];
            if (fb + 2 * NTHREADS < NF4) vout[fb + 2 * NTHREADS] = tile[t + 2 * NTHREADS];
        }

        if (i == 0) {
            __syncthreads();                            // all tile reads done
            tile[t]                = p0;                // stage tile1
            tile[t + NTHREADS]     = p1;
            tile[t + 2 * NTHREADS] = p2;
            __syncthreads();                            // tile1 visible
        }
    }

    // Per-block deterministic reduction (acc=0 for invalid threads).
#pragma unroll
    for (int off = 32; off > 0; off >>= 1)
        acc += __shfl_down(acc, off, 64);
    if ((t & 63) == 0) sred[t >> 6] = acc;
    __syncthreads();
    if (t == 0) {
        float tot = 0.0f;
#pragma unroll
        for (int i = 0; i < NTHREADS / 64; ++i) tot += sred[i];
        partials[blockIdx.x] = tot;
    }
}

// ---------------------------------------------------------------------------
// Loss kernel: sum partials in fixed order -> loss (cross-block sync point).
// ---------------------------------------------------------------------------
__global__ __launch_bounds__(256) void loss_kernel(const float* __restrict__ partials,
                                                   int n, float* __restrict__ loss_out) {
    __shared__ float sdata[4];
    float acc = 0.0f;
    for (int i = threadIdx.x; i < n; i += 256) acc += partials[i];
#pragma unroll
    for (int off = 32; off > 0; off >>= 1)
        acc += __shfl_down(acc, off, 64);
    if ((threadIdx.x & 63) == 0) sdata[threadIdx.x >> 6] = acc;
    __syncthreads();
    if (threadIdx.x == 0) {
        const float tot = sdata[0] + sdata[1] + sdata[2] + sdata[3];
        loss_out[0] = 1.0f / (tot + 1e-6f);
    }
}

extern "C" void kernel_launch(void* const* d_in, const int* in_sizes, int n_in,
                              void* d_out, int out_size, void* d_ws, size_t ws_size,
                              hipStream_t stream) {
    const float4* pts  = (const float4*)d_in[0];
    const float* x     = (const float*)d_in[1];
    const float* y     = (const float*)d_in[2];
    const float* z     = (const float*)d_in[3];
    const float* roll  = (const float*)d_in[4];
    const float* pitch = (const float*)d_in[5];
    const float* yaw   = (const float*)d_in[6];

    float* out   = (float*)d_out;   // [0..12M) verts, [12M] loss
    float* parts = (float*)d_ws;    // NBLOCKS_P floats

    proj_kernel<<<NBLOCKS_P, NTHREADS, 0, stream>>>(pts, x, y, z, roll, pitch, yaw,
                                                    (float4*)out, parts);
    loss_kernel<<<1, 256, 0, stream>>>(parts, NBLOCKS_P, out + (size_t)3 * N_PTS);
}